// Round 6
// baseline (153.637 us; speedup 1.0000x reference)
//
#include <hip/hip_runtime.h>

// MinibatchDiscrimination: B=512, IN=512, OUT=64, KD=8 (fp32 in/out)
// out[i, 0:512] = x[i, :]
// out[i, 512+o] = sum_j exp(-sum_k |M[i,o,k] - M[j,o,k]|),  M = x @ T
//
// R10 = R9 + __launch_bounds__(512, 2).
//  R9's rocprof: VGPR_Count=128, WRITE_SIZE=139.5MB (scratch!), FETCH=113MB
//  -> the fa/fb prefetch + Bv frags spilled to scratch (1064 B/thread of
//  spill writes), turning the load/VALU overlap into an HBM round-trip.
//  launch_bounds(512,2): 2 waves/EU = 8 waves/CU = exactly our 1 block ->
//  VGPR cap 256 (8 waves/CU per m69), fits the ~170 live regs with slack.
//
// Structure (R9): ONE kernel, no cross-block sync (R8's fence/spin storm),
//  redundant per-block recompute, latency-engineered.
//  Block (o=bx>>2, ic=bx&3), 512 thr = 8 waves, grid 256 = 1 block/CU.
//  Floors: phase-1 redundant x-read 1MB/CU over CU<->L2 ~7.4us; phase-2
//  pairs 65536 pairs x 18 VALU / 128 lanes ~3.8us, interleaved into the
//  phase-1 load shadows. 4 rounds: round r MFMA-computes M-quarter
//  (ic+r)&3 (full K=512); pairs pass over quarter (ic+r-1)&3 sits between
//  load-issue and pack+MFMA. mi rows = quarter ic (round 0). B-frags
//  staged to LDS bf16 once, preloaded to 64 VGPR, reused all rounds.
//  M stored to LDS s[512][SROW=12] pre-scaled by log2e -> exp2 in pairs.
//  Total model: 40.5us unconditional ws-poison fill + ~9us launch/fixed
//  + ~11us kernel ~ 60us.

#define B_    512
#define IN_   512
#define OUT_  64
#define ROW_  576
#define ROW4_ 144
#define SROW  12           // padded M-row stride in floats (48 B, 16B-aligned)
#define LOG2E 1.44269504088896340736f

typedef short short8 __attribute__((ext_vector_type(8)));
typedef float f32x4  __attribute__((ext_vector_type(4)));

__device__ __forceinline__ unsigned short f2bf(float f) {
    // round-half-up truncation to bf16; exp(-d) suppression makes the
    // 0.4% relative error invisible (non-self d ~ 200, self-term exact 0)
    return (unsigned short)((__float_as_uint(f) + 0x8000u) >> 16);
}
__device__ __forceinline__ unsigned pack_bf2(float lo, float hi) {
    unsigned a = (__float_as_uint(lo) + 0x8000u) >> 16;
    unsigned b = (__float_as_uint(hi) + 0x8000u) & 0xFFFF0000u;
    return a | b;
}

__global__ __launch_bounds__(512, 2)
void fused_kernel(const float* __restrict__ x, const float* __restrict__ T,
                  float* __restrict__ out) {
    __shared__ __attribute__((aligned(16))) float s[B_ * SROW];   // 24 KB M-slice
    __shared__ unsigned short btT[8][520];                        // 8.1 KB T^T bf16
    __shared__ float s2[4][128];                                  // 2 KB partials

    int t  = threadIdx.x;
    int bx = blockIdx.x;
    int o  = bx >> 2;
    int ic = bx & 3;

    // side job: copy this block's 4KB share of x into out cols 0..511
    if (t < 256) {
        int v = bx * 256 + t;                     // [0, 65536) float4s of x
        ((float4*)out)[(v >> 7) * ROW4_ + (v & 127)] = ((const float4*)x)[v];
    }

    int lane = t & 63, w = t >> 6;                // 8 waves
    int r = lane & 15, q = lane >> 4;

    float4 fa[8], fb[8];                          // x prefetch regs (64 VGPR)

    // ---- round 0 load issue (quarter ic), first K-half ----
    const float* pa0 = x + (ic * 128 + w * 16 + r) * IN_ + q * 8;
    #pragma unroll
    for (int kt = 0; kt < 8; ++kt) {
        fa[kt] = *(const float4*)(pa0 + kt * 32);
        fb[kt] = *(const float4*)(pa0 + kt * 32 + 4);
    }

    // ---- stage T[:,o,:]^T as bf16: thread t handles k=t ----
    {
        const float* tp = T + t * (OUT_ * 8) + o * 8;
        float4 c0 = *(const float4*)tp;
        float4 c1 = *(const float4*)(tp + 4);
        btT[0][t] = f2bf(c0.x); btT[1][t] = f2bf(c0.y);
        btT[2][t] = f2bf(c0.z); btT[3][t] = f2bf(c0.w);
        btT[4][t] = f2bf(c1.x); btT[5][t] = f2bf(c1.y);
        btT[6][t] = f2bf(c1.z); btT[7][t] = f2bf(c1.w);
    }
    __syncthreads();

    // ---- preload all 16 B-frags once (reused every round; 64 VGPR) ----
    short8 Bv[16];
    {
        int rb = r & 7;                           // cols 8-15 duplicate kd 0-7;
        #pragma unroll                            // their C columns are discarded
        for (int kt = 0; kt < 16; ++kt)
            Bv[kt] = *(const short8*)&btT[rb][q * 8 + kt * 32];
    }

    auto mfma8 = [&](f32x4& ac, int kbase) {
        #pragma unroll
        for (int kt = 0; kt < 8; ++kt) {
            union { unsigned u[4]; short8 v; } A;
            A.u[0] = pack_bf2(fa[kt].x, fa[kt].y);
            A.u[1] = pack_bf2(fa[kt].z, fa[kt].w);
            A.u[2] = pack_bf2(fb[kt].x, fb[kt].y);
            A.u[3] = pack_bf2(fb[kt].z, fb[kt].w);
            ac = __builtin_amdgcn_mfma_f32_16x16x32_bf16(A.v, Bv[kt + kbase], ac, 0, 0, 0);
        }
    };
    auto load8 = [&](const float* pa, int kbase) {
        #pragma unroll
        for (int kt = 0; kt < 8; ++kt) {
            fa[kt] = *(const float4*)(pa + (kt + kbase) * 32);
            fb[kt] = *(const float4*)(pa + (kt + kbase) * 32 + 4);
        }
    };
    auto writeRows = [&](const f32x4& ac, int row0) {
        // C/D map: row = q*4+rr, col = r -> M row = row0+q*4+rr, kd = r (<8)
        if (r < 8) {
            #pragma unroll
            for (int rr = 0; rr < 4; ++rr)
                s[(row0 + q * 4 + rr) * SROW + r] = ac[rr] * LOG2E;
        }
    };

    // ---- round 0 compute (quarter ic): no pairs to overlap yet ----
    {
        f32x4 acc = {0.f, 0.f, 0.f, 0.f};
        mfma8(acc, 0);
        load8(pa0, 8);
        mfma8(acc, 8);
        writeRows(acc, ic * 128 + w * 16);
    }
    __syncthreads();

    // ---- mi: this thread's own M row (quarter ic, just computed) ----
    int il = t & 127, win = t >> 7;               // win wave-uniform (2 waves/win)
    float m0, m1, m2, m3, m4, m5, m6, m7;
    {
        const float* p = s + (ic * 128 + il) * SROW;
        float4 lo = *(const float4*)p;
        float4 hi = *(const float4*)(p + 4);
        m0 = lo.x; m1 = lo.y; m2 = lo.z; m3 = lo.w;
        m4 = hi.x; m5 = hi.y; m6 = hi.z; m7 = hi.w;
    }
    float accp = 0.f;

    auto pairs16 = [&](const float*& sj) {
        #pragma unroll
        for (int jj = 0; jj < 16; ++jj) {
            float4 vlo = *(const float4*)sj;       // wave-uniform -> broadcast
            float4 vhi = *(const float4*)(sj + 4);
            sj += SROW;
            float d = fabsf(m0 - vlo.x) + fabsf(m1 - vlo.y)
                    + fabsf(m2 - vlo.z) + fabsf(m3 - vlo.w)
                    + fabsf(m4 - vhi.x) + fabsf(m5 - vhi.y)
                    + fabsf(m6 - vhi.z) + fabsf(m7 - vhi.w);
            accp += exp2f(-d);                     // M pre-scaled by log2e
        }
    };

    // ---- rounds 1..3: loads(quarter qr) || pairs(quarter qp, ready) ----
    #pragma unroll
    for (int rd = 1; rd < 4; ++rd) {
        int qr = (ic + rd) & 3;                   // quarter this round computes
        int qp = (ic + rd - 1) & 3;               // quarter pairs consumes
        const float* pa = x + (qr * 128 + w * 16 + r) * IN_ + q * 8;
        const float* sj = s + (qp * 128 + win * 32) * SROW;

        load8(pa, 0);                             // issue K-half 0
        pairs16(sj);                              // VALU fills load latency
        f32x4 acc = {0.f, 0.f, 0.f, 0.f};
        mfma8(acc, 0);
        load8(pa, 8);                             // issue K-half 1
        pairs16(sj);
        mfma8(acc, 8);
        writeRows(acc, qr * 128 + w * 16);
        __syncthreads();
    }

    // ---- final pairs pass (quarter (ic+3)&3) ----
    {
        int qp = (ic + 3) & 3;
        const float* sj = s + (qp * 128 + win * 32) * SROW;
        pairs16(sj);
        pairs16(sj);
    }

    s2[win][il] = accp;
    __syncthreads();

    // exclusive final store: this block owns (o, i) for i in [ic*128, +128)
    if (t < 128) {
        float v = s2[0][t] + s2[1][t] + s2[2][t] + s2[3][t];
        out[(ic * 128 + t) * ROW_ + IN_ + o] = v;
    }
}

extern "C" void kernel_launch(void* const* d_in, const int* in_sizes, int n_in,
                              void* d_out, int out_size, void* d_ws, size_t ws_size,
                              hipStream_t stream) {
    const float* x = (const float*)d_in[0];   // [512, 512]
    const float* T = (const float*)d_in[1];   // [512, 64, 8]
    float* out = (float*)d_out;               // [512, 576]
    (void)d_ws; (void)ws_size;                // workspace unused (fill is unconditional)

    fused_kernel<<<256, 512, 0, stream>>>(x, T, out);
}

// Round 7
// 153.272 us; speedup vs baseline: 1.0024x; 1.0024x over previous
//
#include <hip/hip_runtime.h>

// MinibatchDiscrimination: B=512, IN=512, OUT=64, KD=8 (fp32 in/out)
// out[i, 0:512] = x[i, :]
// out[i, 512+o] = sum_j exp(-sum_k |M[i,o,k] - M[j,o,k]|),  M = x @ T
//
// R11 = R9 pipeline with ALL register arrays eliminated (rule #20).
//  Evidence: R10 (launch_bounds 512,2) produced IDENTICAL code to R9
//  (VGPR=128, WRITE=139.5MB scratch) -> the spill is NOT a reg-cap issue:
//  fa[8]/fb[8]/Bv[16] indexed through lambda args went to scratch at isel
//  (runtime-indexed arrays -> local memory), unfixable by launch bounds.
//  Fix: individually named a0..a7/b0..b7/Bv0..Bv15 + macro-expanded
//  loads/MFMAs so every access is compile-time static. ~160 live regs
//  under the 256 cap from __launch_bounds__(512,2).
//
// Structure (R9): ONE kernel, no cross-block sync, redundant per-block
//  recompute, latency-engineered. Block (o=bx>>2, ic=bx&3), 512 thr =
//  8 waves, grid 256 = 1 block/CU.
//  4 rounds: round rd MFMA-computes M-quarter (ic+rd)&3 (full K=512);
//  pairs pass over quarter (ic+rd-1)&3 sits between load-issue and
//  pack+MFMA -> pairs VALU fills the x-load L2 latency. mi = own row
//  (quarter ic, round 0). T^T staged to LDS bf16 once, preloaded to
//  Bv0..15, reused all rounds. M -> LDS s[512][SROW=12] pre-scaled by
//  log2e -> bare exp2 in pairs.
//  Floors: 1MB x/CU via L2 ~7.4us ; pairs 65536x18 VALU /128 lanes ~3.8us.
//  Total model: 40.5us unconditional fill + ~9us launch/fixed + kernel.

#define B_    512
#define IN_   512
#define OUT_  64
#define ROW_  576
#define ROW4_ 144
#define SROW  12           // padded M-row stride in floats (48 B, 16B-aligned)
#define LOG2E 1.44269504088896340736f

typedef short short8 __attribute__((ext_vector_type(8)));
typedef float f32x4  __attribute__((ext_vector_type(4)));

__device__ __forceinline__ unsigned short f2bf(float f) {
    // round-half-up truncation to bf16; exp(-d) suppression makes the
    // 0.4% relative error invisible (non-self d ~ 200, self-term exact 0)
    return (unsigned short)((__float_as_uint(f) + 0x8000u) >> 16);
}
__device__ __forceinline__ unsigned pack_bf2(float lo, float hi) {
    unsigned a = (__float_as_uint(lo) + 0x8000u) >> 16;
    unsigned b = (__float_as_uint(hi) + 0x8000u) & 0xFFFF0000u;
    return a | b;
}

// issue 16 global_load_dwordx4 into named regs (kb = 0 or 8, compile-time)
#define LOADK(pa, kb) do {                                                  \
    a0 = *(const float4*)((pa) + ((kb)+0)*32);                              \
    b0 = *(const float4*)((pa) + ((kb)+0)*32 + 4);                          \
    a1 = *(const float4*)((pa) + ((kb)+1)*32);                              \
    b1 = *(const float4*)((pa) + ((kb)+1)*32 + 4);                          \
    a2 = *(const float4*)((pa) + ((kb)+2)*32);                              \
    b2 = *(const float4*)((pa) + ((kb)+2)*32 + 4);                          \
    a3 = *(const float4*)((pa) + ((kb)+3)*32);                              \
    b3 = *(const float4*)((pa) + ((kb)+3)*32 + 4);                          \
    a4 = *(const float4*)((pa) + ((kb)+4)*32);                              \
    b4 = *(const float4*)((pa) + ((kb)+4)*32 + 4);                          \
    a5 = *(const float4*)((pa) + ((kb)+5)*32);                              \
    b5 = *(const float4*)((pa) + ((kb)+5)*32 + 4);                          \
    a6 = *(const float4*)((pa) + ((kb)+6)*32);                              \
    b6 = *(const float4*)((pa) + ((kb)+6)*32 + 4);                          \
    a7 = *(const float4*)((pa) + ((kb)+7)*32);                              \
    b7 = *(const float4*)((pa) + ((kb)+7)*32 + 4);                          \
} while (0)

#define MFMA1(fa_, fb_, BV) do {                                            \
    union { unsigned u[4]; short8 v; } A_;                                  \
    A_.u[0] = pack_bf2(fa_.x, fa_.y);                                       \
    A_.u[1] = pack_bf2(fa_.z, fa_.w);                                       \
    A_.u[2] = pack_bf2(fb_.x, fb_.y);                                       \
    A_.u[3] = pack_bf2(fb_.z, fb_.w);                                       \
    acc = __builtin_amdgcn_mfma_f32_16x16x32_bf16(A_.v, BV, acc, 0, 0, 0);  \
} while (0)

#define MFMA_LO() do {                                                      \
    MFMA1(a0, b0, Bv0); MFMA1(a1, b1, Bv1);                                 \
    MFMA1(a2, b2, Bv2); MFMA1(a3, b3, Bv3);                                 \
    MFMA1(a4, b4, Bv4); MFMA1(a5, b5, Bv5);                                 \
    MFMA1(a6, b6, Bv6); MFMA1(a7, b7, Bv7);                                 \
} while (0)

#define MFMA_HI() do {                                                      \
    MFMA1(a0, b0, Bv8);  MFMA1(a1, b1, Bv9);                                \
    MFMA1(a2, b2, Bv10); MFMA1(a3, b3, Bv11);                               \
    MFMA1(a4, b4, Bv12); MFMA1(a5, b5, Bv13);                               \
    MFMA1(a6, b6, Bv14); MFMA1(a7, b7, Bv15);                               \
} while (0)

// C/D map: row = q*4+rr, col = r -> M row = row0+q*4+rr, kd = r (<8 real)
#define WRITEROWS(row0) do { if (r < 8) {                                   \
    s[((row0) + q*4 + 0)*SROW + r] = acc[0] * LOG2E;                        \
    s[((row0) + q*4 + 1)*SROW + r] = acc[1] * LOG2E;                        \
    s[((row0) + q*4 + 2)*SROW + r] = acc[2] * LOG2E;                        \
    s[((row0) + q*4 + 3)*SROW + r] = acc[3] * LOG2E; } } while (0)

#define PAIRS16() do {                                                      \
    _Pragma("unroll")                                                       \
    for (int jj = 0; jj < 16; ++jj) {                                       \
        float4 vlo = *(const float4*)sj;   /* wave-uniform -> broadcast */  \
        float4 vhi = *(const float4*)(sj + 4);                              \
        sj += SROW;                                                         \
        float d = fabsf(m0 - vlo.x) + fabsf(m1 - vlo.y)                     \
                + fabsf(m2 - vlo.z) + fabsf(m3 - vlo.w)                     \
                + fabsf(m4 - vhi.x) + fabsf(m5 - vhi.y)                     \
                + fabsf(m6 - vhi.z) + fabsf(m7 - vhi.w);                    \
        accp += exp2f(-d);             /* M pre-scaled by log2e */          \
    }                                                                       \
} while (0)

__global__ __launch_bounds__(512, 2)
void fused_kernel(const float* __restrict__ x, const float* __restrict__ T,
                  float* __restrict__ out) {
    __shared__ __attribute__((aligned(16))) float s[B_ * SROW];   // 24 KB M-slice
    __shared__ unsigned short btT[8][520];                        // 8.1 KB T^T bf16
    __shared__ float s2[4][128];                                  // 2 KB partials

    int t  = threadIdx.x;
    int bx = blockIdx.x;
    int o  = bx >> 2;
    int ic = bx & 3;

    // side job: copy this block's 4KB share of x into out cols 0..511
    if (t < 256) {
        int v = bx * 256 + t;                     // [0, 65536) float4s of x
        ((float4*)out)[(v >> 7) * ROW4_ + (v & 127)] = ((const float4*)x)[v];
    }

    int lane = t & 63, w = t >> 6;                // 8 waves
    int r = lane & 15, q = lane >> 4;

    float4 a0, a1, a2, a3, a4, a5, a6, a7;        // x prefetch (64 VGPR)
    float4 b0, b1, b2, b3, b4, b5, b6, b7;

    // ---- round 0 load issue (quarter ic), K-half 0 ----
    const float* pa0 = x + (ic * 128 + w * 16 + r) * IN_ + q * 8;
    LOADK(pa0, 0);

    // ---- stage T[:,o,:]^T as bf16: thread t handles k=t ----
    {
        const float* tp = T + t * (OUT_ * 8) + o * 8;
        float4 c0 = *(const float4*)tp;
        float4 c1 = *(const float4*)(tp + 4);
        btT[0][t] = f2bf(c0.x); btT[1][t] = f2bf(c0.y);
        btT[2][t] = f2bf(c0.z); btT[3][t] = f2bf(c0.w);
        btT[4][t] = f2bf(c1.x); btT[5][t] = f2bf(c1.y);
        btT[6][t] = f2bf(c1.z); btT[7][t] = f2bf(c1.w);
    }
    __syncthreads();

    // ---- preload all 16 B-frags once (named; reused every round) ----
    short8 Bv0, Bv1, Bv2, Bv3, Bv4, Bv5, Bv6, Bv7;
    short8 Bv8, Bv9, Bv10, Bv11, Bv12, Bv13, Bv14, Bv15;
    {
        int rb = r & 7;                           // cols 8-15 duplicate kd 0-7;
        const unsigned short* bp = &btT[rb][q * 8];   // their C cols discarded
        Bv0  = *(const short8*)(bp + 0 * 32);
        Bv1  = *(const short8*)(bp + 1 * 32);
        Bv2  = *(const short8*)(bp + 2 * 32);
        Bv3  = *(const short8*)(bp + 3 * 32);
        Bv4  = *(const short8*)(bp + 4 * 32);
        Bv5  = *(const short8*)(bp + 5 * 32);
        Bv6  = *(const short8*)(bp + 6 * 32);
        Bv7  = *(const short8*)(bp + 7 * 32);
        Bv8  = *(const short8*)(bp + 8 * 32);
        Bv9  = *(const short8*)(bp + 9 * 32);
        Bv10 = *(const short8*)(bp + 10 * 32);
        Bv11 = *(const short8*)(bp + 11 * 32);
        Bv12 = *(const short8*)(bp + 12 * 32);
        Bv13 = *(const short8*)(bp + 13 * 32);
        Bv14 = *(const short8*)(bp + 14 * 32);
        Bv15 = *(const short8*)(bp + 15 * 32);
    }

    // ---- round 0 compute (quarter ic): no pairs to overlap yet ----
    f32x4 acc = {0.f, 0.f, 0.f, 0.f};
    MFMA_LO();
    LOADK(pa0, 8);
    MFMA_HI();
    WRITEROWS(ic * 128 + w * 16);
    __syncthreads();

    // ---- mi: this thread's own M row (quarter ic, just computed) ----
    int il = t & 127, win = t >> 7;               // win wave-uniform (2 waves/win)
    float m0, m1, m2, m3, m4, m5, m6, m7;
    {
        const float* p = s + (ic * 128 + il) * SROW;
        float4 lo = *(const float4*)p;
        float4 hi = *(const float4*)(p + 4);
        m0 = lo.x; m1 = lo.y; m2 = lo.z; m3 = lo.w;
        m4 = hi.x; m5 = hi.y; m6 = hi.z; m7 = hi.w;
    }
    float accp = 0.f;

    // ---- rounds 1..3: loads(quarter qr) || pairs(quarter qp, ready) ----
    #pragma unroll
    for (int rd = 1; rd < 4; ++rd) {
        int qr = (ic + rd) & 3;                   // quarter this round computes
        int qp = (ic + rd - 1) & 3;               // quarter pairs consumes
        const float* pa = x + (qr * 128 + w * 16 + r) * IN_ + q * 8;
        const float* sj = s + (qp * 128 + win * 32) * SROW;

        LOADK(pa, 0);                             // issue K-half 0
        PAIRS16();                                // VALU fills load latency
        acc = (f32x4){0.f, 0.f, 0.f, 0.f};
        MFMA_LO();
        LOADK(pa, 8);                             // issue K-half 1
        PAIRS16();
        MFMA_HI();
        WRITEROWS(qr * 128 + w * 16);
        __syncthreads();
    }

    // ---- final pairs pass (quarter (ic+3)&3) ----
    {
        int qp = (ic + 3) & 3;
        const float* sj = s + (qp * 128 + win * 32) * SROW;
        PAIRS16();
        PAIRS16();
    }

    s2[win][il] = accp;
    __syncthreads();

    // exclusive final store: this block owns (o, i) for i in [ic*128, +128)
    if (t < 128) {
        float v = s2[0][t] + s2[1][t] + s2[2][t] + s2[3][t];
        out[(ic * 128 + t) * ROW_ + IN_ + o] = v;
    }
}

extern "C" void kernel_launch(void* const* d_in, const int* in_sizes, int n_in,
                              void* d_out, int out_size, void* d_ws, size_t ws_size,
                              hipStream_t stream) {
    const float* x = (const float*)d_in[0];   // [512, 512]
    const float* T = (const float*)d_in[1];   // [512, 64, 8]
    float* out = (float*)d_out;               // [512, 576]
    (void)d_ws; (void)ws_size;                // workspace unused (fill is unconditional)

    fused_kernel<<<256, 512, 0, stream>>>(x, T, out);
}

// Round 9
// 118.313 us; speedup vs baseline: 1.2986x; 1.2955x over previous
//
#include <hip/hip_runtime.h>

// MinibatchDiscrimination: B=512, IN=512, OUT=64, KD=8 (fp32 in/out)
// out[i, 0:512] = x[i, :]
// out[i, 512+o] = sum_j exp(-sum_k |M[i,o,k] - M[j,o,k]|),  M = x @ T
//
// R13 = R12 compile fix (macro local "B_" collided with #define B_) +
//  (a) fully-dense x loads: lane*4 contiguous (16 lines/inst, probe floor)
//  (b) pairs interleaved into the chunk loop (chunks rotated so own mi
//      rows finish at step 1; 6/8 windows hidden under later chunks).
//  Rationale (R5/R9/R11): one-kernel redundant recompute is the only
//  structure under ~70us (fill 40.5us unconditional + ~10us/launch);
//  x must be read with dense lines (scattered 16B rows = 64 probes/inst
//  was R5's 27us stall); no register arrays anywhere (isel scratch).
//  Block (o=bx>>2, ic=bx&3), grid 256 = 1 block/CU, 1024 thr = 16 waves.
//  Phase 1 (8 steps): step c computes chunk ch=(c+2ic)&7 (64 rows x 512 k):
//    GLOAD(next chunk) dense -> pack bf16 -> ds_write_b64 2-XOR-swizzled;
//    16 waves = (rs row-subtile) x (kq k-quarter); 4 MFMA/wave/step;
//    kq-partials via sred LDS; kq==0 writes M rows *LOG2E to s[512][12].
//    From step 2: PAIRS8 over window ch(c-2) (8 j/thread, bcast reads).
//  Tail: PAIRS8 over ch(6), ch(7); s2[8][128] reduce; exclusive store.
//  Swizzle: physical unit = u ^ (row&7) ^ ((u>>3)&7)  (u = 8-bf16 unit):
//    write-side 8B stores conflict-free (4cy min), read-side b128 8cy min.
//  Floors: x probes 16K lines ~7us ~ per-XCD L2 BW 7.4us (the wall);
//  LDS ~4.3us, pairs ~3.8us hidden. Model: 40.5 + ~10 + ~11 = ~62.

#define B_    512
#define IN_   512
#define OUT_  64
#define ROW_  576
#define ROW4_ 144
#define SROW  12           // padded M-row stride in floats (48 B, 16B-aligned)
#define LOG2E 1.44269504088896340736f

typedef short short8 __attribute__((ext_vector_type(8)));
typedef float f32x4  __attribute__((ext_vector_type(4)));
typedef unsigned u32x2 __attribute__((ext_vector_type(2)));

__device__ __forceinline__ unsigned short f2bf(float f) {
    // round-half-up truncation to bf16 (proven absmax-safe in R4/R7)
    return (unsigned short)((__float_as_uint(f) + 0x8000u) >> 16);
}
__device__ __forceinline__ unsigned pack_bf2(float lo, float hi) {
    unsigned a = (__float_as_uint(lo) + 0x8000u) >> 16;
    unsigned b = (__float_as_uint(hi) + 0x8000u) & 0xFFFF0000u;
    return a | b;
}

// dense chunk loads: wave handles rows wid+{0,16,32,48}; per row 2 halves;
// lane covers 16B contiguous -> 16 cache lines / inst (probe-optimal)
#define GLOAD(chp_) do {                                                      \
    const float* xp_ = x + ((chp_) * 64 + wid) * 512 + lane * 4;              \
    g00 = *(const float4*)(xp_);           g01 = *(const float4*)(xp_ + 256); \
    g10 = *(const float4*)(xp_ + 8192);    g11 = *(const float4*)(xp_ + 8448);\
    g20 = *(const float4*)(xp_ + 16384);   g21 = *(const float4*)(xp_ + 16640);\
    g30 = *(const float4*)(xp_ + 24576);   g31 = *(const float4*)(xp_ + 24832);\
} while (0)

// pack one row-half to bf16 and write 8B, 2-XOR swizzle:
// logical unit u = h*32 + (lane>>1); phys = u ^ (row&7) ^ ((u>>3)&7)
#define XW1(g_, rr_, h_) do {                                                 \
    unsigned p0_ = pack_bf2(g_.x, g_.y), p1_ = pack_bf2(g_.z, g_.w);          \
    int sw_ = ((h_) * 32 + (lane >> 1)) ^ (wid & 7)                           \
            ^ (((h_) * 4 + (lane >> 4)) & 7);                                 \
    *(u32x2*)&xb[(wid + (rr_) * 16) * 512 + sw_ * 8 + (lane & 1) * 4]         \
        = (u32x2){p0_, p1_};                                                  \
} while (0)

#define XWRITE() do {                                                         \
    XW1(g00, 0, 0); XW1(g01, 0, 1);                                           \
    XW1(g10, 1, 0); XW1(g11, 1, 1);                                           \
    XW1(g20, 2, 0); XW1(g21, 2, 1);                                           \
    XW1(g30, 3, 0); XW1(g31, 3, 1);                                           \
} while (0)

// one MFMA k-step: A from swizzled bf16 LDS, B from btT. kt_ literal 0..3.
// A logical unit u = kq*16 + kt*4 + q; phys = u ^ (r&7) ^ ((u>>3)&7),
// (u>>3)&7 = (kq*2 + (kt>=2)) & 7  (wave-uniform XOR: bank-neutral)
#define CSTEP(kt_) do {                                                       \
    short8 Av_ = *(const short8*)&xb[lr_ * 512 +                              \
        (((kq * 16 + (kt_) * 4 + q) ^ (r & 7)                                 \
          ^ ((kq * 2 + ((kt_) >> 1)) & 7)) * 8)];                             \
    short8 Bt_ = *(const short8*)&btT[r & 7][q * 8 + kq * 128 + (kt_) * 32];  \
    acc = __builtin_amdgcn_mfma_f32_16x16x32_bf16(Av_, Bt_, acc, 0, 0, 0);    \
} while (0)

// 8-j pairs slice over window w_ (thread's fixed offset win*8)
#define PAIRS8(w_) do {                                                       \
    const float* sj_ = s + ((w_) * 64 + win * 8) * SROW;                      \
    _Pragma("unroll")                                                         \
    for (int jj_ = 0; jj_ < 8; ++jj_) {                                       \
        float4 vlo_ = *(const float4*)sj_;   /* wave-uniform -> bcast */      \
        float4 vhi_ = *(const float4*)(sj_ + 4);                              \
        sj_ += SROW;                                                          \
        float d_ = fabsf(m0 - vlo_.x) + fabsf(m1 - vlo_.y)                    \
                 + fabsf(m2 - vlo_.z) + fabsf(m3 - vlo_.w)                    \
                 + fabsf(m4 - vhi_.x) + fabsf(m5 - vhi_.y)                    \
                 + fabsf(m6 - vhi_.z) + fabsf(m7 - vhi_.w);                   \
        accp += exp2f(-d_);                  /* s pre-scaled by log2e */      \
    }                                                                         \
} while (0)

__global__ __launch_bounds__(1024, 4)
void fused_kernel(const float* __restrict__ x, const float* __restrict__ T,
                  float* __restrict__ out) {
    __shared__ __attribute__((aligned(16))) unsigned short xb[64 * 512]; // 64 KB chunk
    __shared__ __attribute__((aligned(16))) float s[B_ * SROW];          // 24 KB M-slice
    __shared__ unsigned short btT[8][520];                               // 8.1 KB T^T
    __shared__ __attribute__((aligned(16))) f32x4 sred[4][3][64];        // 12 KB
    __shared__ float s2[8][128];                                         // 4 KB

    int t  = threadIdx.x;
    int bx = blockIdx.x;
    int o  = bx >> 2;
    int ic = bx & 3;
    int lane = t & 63, wid = t >> 6;          // 16 waves
    int r = lane & 15, q = lane >> 4;
    int rs = wid & 3, kq = wid >> 2;          // row-subtile x k-quarter
    int lr_ = rs * 16 + r;                    // chunk-local row this lane MFMAs
    int il = t & 127, win = t >> 7;           // pairs: i-local x j-offset group

    // side job: copy this block's 4KB share of x into out cols 0..511
    if (t < 256) {
        int v = bx * 256 + t;                 // [0, 65536) float4s of x
        ((float4*)out)[(v >> 7) * ROW4_ + (v & 127)] = ((const float4*)x)[v];
    }

    // stage T[:,o,:]^T as bf16: thread t (<512) handles k=t
    if (t < 512) {
        const float* tp = T + t * (OUT_ * 8) + o * 8;
        float4 c0 = *(const float4*)tp;
        float4 c1 = *(const float4*)(tp + 4);
        btT[0][t] = f2bf(c0.x); btT[1][t] = f2bf(c0.y);
        btT[2][t] = f2bf(c0.z); btT[3][t] = f2bf(c0.w);
        btT[4][t] = f2bf(c1.x); btT[5][t] = f2bf(c1.y);
        btT[6][t] = f2bf(c1.z); btT[7][t] = f2bf(c1.w);
    }

    float4 g00, g01, g10, g11, g20, g21, g30, g31;   // stage regs (32 VGPR)
    float m0, m1, m2, m3, m4, m5, m6, m7;            // own M row
    float accp = 0.f;

    // prologue: stage chunk ch(0) = 2*ic
    GLOAD(2 * ic);
    XWRITE();
    __syncthreads();

    // ---- phase 1: 8 steps; step c computes chunk (c+2ic)&7, overlapped ----
    #pragma unroll
    for (int c = 0; c < 8; ++c) {
        int chc = (c + 2 * ic) & 7;
        if (c < 7) GLOAD((c + 1 + 2 * ic) & 7);   // issue next loads early
        if (c == 2) {                             // own mi rows ready (steps 0,1)
            const float* p = s + (ic * 128 + il) * SROW;
            float4 lo = *(const float4*)p;
            float4 hi = *(const float4*)(p + 4);
            m0 = lo.x; m1 = lo.y; m2 = lo.z; m3 = lo.w;
            m4 = hi.x; m5 = hi.y; m6 = hi.z; m7 = hi.w;
        }
        if (c >= 2) PAIRS8((c - 2 + 2 * ic) & 7); // hidden under load latency
        f32x4 acc = {0.f, 0.f, 0.f, 0.f};
        CSTEP(0); CSTEP(1); CSTEP(2); CSTEP(3);
        if (kq) sred[rs][kq - 1][lane] = acc;
        __syncthreads();                          // xb reads + sred done
        if (kq == 0) {
            acc += sred[rs][0][lane];
            acc += sred[rs][1][lane];
            acc += sred[rs][2][lane];
            // C/D map: row=q*4+rr, col=r -> M row = chc*64+rs*16+q*4+rr, kd=r(<8)
            if (r < 8) {
                int rb_ = chc * 64 + rs * 16 + q * 4;
                s[(rb_ + 0) * SROW + r] = acc[0] * LOG2E;
                s[(rb_ + 1) * SROW + r] = acc[1] * LOG2E;
                s[(rb_ + 2) * SROW + r] = acc[2] * LOG2E;
                s[(rb_ + 3) * SROW + r] = acc[3] * LOG2E;
            }
        }
        if (c < 7) XWRITE();                      // stage next into freed xb
        __syncthreads();                          // xb(next) + s(chc) ready
    }

    // ---- tail: last two windows ----
    PAIRS8((6 + 2 * ic) & 7);
    PAIRS8((7 + 2 * ic) & 7);

    s2[win][il] = accp;
    __syncthreads();

    // exclusive final store: this block owns (o, i) for i in [ic*128, +128)
    if (t < 128) {
        float v = s2[0][t] + s2[1][t] + s2[2][t] + s2[3][t]
                + s2[4][t] + s2[5][t] + s2[6][t] + s2[7][t];
        out[(ic * 128 + t) * ROW_ + IN_ + o] = v;
    }
}

extern "C" void kernel_launch(void* const* d_in, const int* in_sizes, int n_in,
                              void* d_out, int out_size, void* d_ws, size_t ws_size,
                              hipStream_t stream) {
    const float* x = (const float*)d_in[0];   // [512, 512]
    const float* T = (const float*)d_in[1];   // [512, 64, 8]
    float* out = (float*)d_out;               // [512, 576]
    (void)d_ws; (void)ws_size;                // ws unused (poison fill unconditional)

    fused_kernel<<<256, 1024, 0, stream>>>(x, T, out);
}